// Round 1
// baseline (488.580 us; speedup 1.0000x reference)
//
#include <hip/hip_runtime.h>
#include <hip/hip_bf16.h>

// GraphEncoder: 2-layer GNN with edge-MLP + scatter-mean.
// Key reformulation:
//   cat(x_dst,x_src)@Wa = (x@Wa_top)[dst] + (x@Wa_bot)[src]
//   mean_agg(relu(pre)@Wb + bb) = mean_agg(relu(pre))@Wb + (cnt>0)*bb
// => per-edge work is just relu(add) + CSR mean aggregation; all GEMMs are N-scale.

#define N_NODES 20000
#define NODE_DIM 128
#define HID 256
#define OUTD 128

// ---------------- utility kernels ----------------

__global__ void zero_int_kernel(int* __restrict__ p, int n) {
    int i = blockIdx.x * blockDim.x + threadIdx.x;
    if (i < n) p[i] = 0;
}

__global__ void hist_kernel(const int* __restrict__ dst, int* __restrict__ cnt, int E) {
    int e = blockIdx.x * blockDim.x + threadIdx.x;
    if (e < E) atomicAdd(&cnt[dst[e]], 1);
}

// single-block exclusive scan over cnt -> row_ptr (and cursor copy), row_ptr[N]=E
__global__ __launch_bounds__(1024) void scan_kernel(const int* __restrict__ cnt,
                                                    int* __restrict__ row_ptr,
                                                    int* __restrict__ cursor, int N) {
    __shared__ int buf[1024];
    int tid = threadIdx.x;
    int running = 0;
    for (int base = 0; base < N; base += 1024) {
        int i = base + tid;
        int v = (i < N) ? cnt[i] : 0;
        buf[tid] = v;
        __syncthreads();
        for (int off = 1; off < 1024; off <<= 1) {
            int t = (tid >= off) ? buf[tid - off] : 0;
            __syncthreads();
            buf[tid] += t;
            __syncthreads();
        }
        int incl = buf[tid];
        int total = buf[1023];
        if (i < N) {
            int ex = running + incl - v;
            row_ptr[i] = ex;
            cursor[i] = ex;
        }
        running += total;
        __syncthreads();
    }
    if (tid == 0) row_ptr[N] = running;
}

__global__ void scatter_kernel(const int* __restrict__ src, const int* __restrict__ dst,
                               int* __restrict__ cursor, int* __restrict__ csr, int E) {
    int e = blockIdx.x * blockDim.x + threadIdx.x;
    if (e < E) {
        int p = atomicAdd(&cursor[dst[e]], 1);
        csr[p] = src[e];
    }
}

// ---------------- f32 tiled GEMM ----------------
// C[M][Nc] = act(A[M][K] @ B[K][Nc](ldb) + bias * gatemask)
// BM=128, BN=128, BK=16, 256 threads, 8x8 per thread (4+4 split to keep LDS reads 2-way max)

#define BM 128
#define BN 128
#define BK 16

__global__ __launch_bounds__(256) void gemm_f32(
    const float* __restrict__ A, int M, int K,
    const float* __restrict__ B, int ldb,
    const float* __restrict__ bias, const int* __restrict__ gate,
    float* __restrict__ C, int Nc, int relu) {
    __shared__ float As[BK][BM + 4];
    __shared__ float Bs[BK][BN + 4];

    const int tid = threadIdx.x;
    const int ty = tid >> 4;   // 0..15
    const int tx = tid & 15;   // 0..15
    const int m0 = blockIdx.x * BM;
    const int n0 = blockIdx.y * BN;

    float acc[8][8];
#pragma unroll
    for (int i = 0; i < 8; i++)
#pragma unroll
        for (int j = 0; j < 8; j++) acc[i][j] = 0.f;

    for (int kt = 0; kt < K; kt += BK) {
        // A tile: 128 rows x 16 k, transposed into As[k][row]
#pragma unroll
        for (int l = 0; l < 2; l++) {
            int p = tid + l * 256;      // 0..511
            int row = p >> 2;           // 0..127
            int c4 = (p & 3) * 4;       // 0,4,8,12
            int gr = m0 + row;
            float4 v = make_float4(0.f, 0.f, 0.f, 0.f);
            if (gr < M) v = *(const float4*)(A + (size_t)gr * K + kt + c4);
            As[c4 + 0][row] = v.x;
            As[c4 + 1][row] = v.y;
            As[c4 + 2][row] = v.z;
            As[c4 + 3][row] = v.w;
        }
        // B tile: 16 k x 128 cols
#pragma unroll
        for (int l = 0; l < 2; l++) {
            int p = tid + l * 256;
            int kk = p >> 5;            // 0..15
            int n4 = (p & 31) * 4;      // 0..124
            float4 v = *(const float4*)(B + (size_t)(kt + kk) * ldb + n0 + n4);
            *(float4*)&Bs[kk][n4] = v;
        }
        __syncthreads();

#pragma unroll
        for (int k = 0; k < BK; k++) {
            float a[8], b[8];
            *(float4*)&a[0] = *(const float4*)&As[k][ty * 4];
            *(float4*)&a[4] = *(const float4*)&As[k][64 + ty * 4];
            *(float4*)&b[0] = *(const float4*)&Bs[k][tx * 4];
            *(float4*)&b[4] = *(const float4*)&Bs[k][64 + tx * 4];
#pragma unroll
            for (int i = 0; i < 8; i++)
#pragma unroll
                for (int j = 0; j < 8; j++) acc[i][j] += a[i] * b[j];
        }
        __syncthreads();
    }

    // epilogue
    float bv[8];
#pragma unroll
    for (int j = 0; j < 8; j++) {
        int c = n0 + ((j < 4) ? (tx * 4 + j) : (64 + tx * 4 + j - 4));
        bv[j] = bias ? bias[c] : 0.f;
    }
#pragma unroll
    for (int i = 0; i < 8; i++) {
        int r = m0 + ((i < 4) ? (ty * 4 + i) : (64 + ty * 4 + i - 4));
        if (r >= M) continue;
        float g = 1.f;
        if (gate) g = (gate[r] > 0) ? 1.f : 0.f;
        float out[8];
#pragma unroll
        for (int j = 0; j < 8; j++) {
            float v = acc[i][j] + bv[j] * g;
            out[j] = relu ? fmaxf(v, 0.f) : v;
        }
        float* cp = C + (size_t)r * Nc + n0;
        *(float4*)(cp + tx * 4) = *(const float4*)&out[0];
        *(float4*)(cp + 64 + tx * 4) = *(const float4*)&out[4];
    }
}

// ---------------- CSR mean aggregation ----------------
// one wave per node: acc = mean_{e in in(n)} relu(Ptop[n] + Pbot[src_e])

template <int H>
__global__ __launch_bounds__(256) void agg_kernel(const float* __restrict__ Ptop,
                                                  const float* __restrict__ Pbot,
                                                  const int* __restrict__ row_ptr,
                                                  const int* __restrict__ csr,
                                                  float* __restrict__ S, int N) {
    constexpr int VPL = H / 64;  // 4 (H=256) or 2 (H=128)
    const int wave = threadIdx.x >> 6;
    const int lane = threadIdx.x & 63;
    const int n = blockIdx.x * (blockDim.x >> 6) + wave;
    if (n >= N) return;

    const int begin = row_ptr[n];
    const int end = row_ptr[n + 1];

    float top[VPL], acc[VPL];
    if constexpr (VPL == 4) {
        float4 t = *(const float4*)(Ptop + (size_t)n * H + lane * 4);
        top[0] = t.x; top[1] = t.y; top[2] = t.z; top[3] = t.w;
    } else {
        float2 t = *(const float2*)(Ptop + (size_t)n * H + lane * 2);
        top[0] = t.x; top[1] = t.y;
    }
#pragma unroll
    for (int i = 0; i < VPL; i++) acc[i] = 0.f;

    for (int e = begin; e < end; e++) {
        int s = csr[e];
        if constexpr (VPL == 4) {
            float4 v = *(const float4*)(Pbot + (size_t)s * H + lane * 4);
            acc[0] += fmaxf(top[0] + v.x, 0.f);
            acc[1] += fmaxf(top[1] + v.y, 0.f);
            acc[2] += fmaxf(top[2] + v.z, 0.f);
            acc[3] += fmaxf(top[3] + v.w, 0.f);
        } else {
            float2 v = *(const float2*)(Pbot + (size_t)s * H + lane * 2);
            acc[0] += fmaxf(top[0] + v.x, 0.f);
            acc[1] += fmaxf(top[1] + v.y, 0.f);
        }
    }

    float inv = (end > begin) ? 1.f / (float)(end - begin) : 0.f;
    if constexpr (VPL == 4) {
        float4 o = make_float4(acc[0] * inv, acc[1] * inv, acc[2] * inv, acc[3] * inv);
        *(float4*)(S + (size_t)n * H + lane * 4) = o;
    } else {
        float2 o = make_float2(acc[0] * inv, acc[1] * inv);
        *(float2*)(S + (size_t)n * H + lane * 2) = o;
    }
}

// ---------------- launch ----------------

extern "C" void kernel_launch(void* const* d_in, const int* in_sizes, int n_in,
                              void* d_out, int out_size, void* d_ws, size_t ws_size,
                              hipStream_t stream) {
    const int N = in_sizes[0] / NODE_DIM;  // 20000
    const int E = in_sizes[1] / 2;         // 640000

    const float* x = (const float*)d_in[0];
    const int* ei = (const int*)d_in[1];
    const int* e_src = ei;
    const int* e_dst = ei + E;
    const float* W1a = (const float*)d_in[2];
    const float* b1a = (const float*)d_in[3];
    const float* W1b = (const float*)d_in[4];
    const float* b1b = (const float*)d_in[5];
    const float* W2a = (const float*)d_in[6];
    const float* b2a = (const float*)d_in[7];
    const float* W2b = (const float*)d_in[8];
    const float* b2b = (const float*)d_in[9];

    char* ws = (char*)d_ws;
    size_t off = 0;
    auto alloc = [&](size_t bytes) {
        size_t o = off;
        off += (bytes + 255) & ~(size_t)255;
        return o;
    };
    int* cnt = (int*)(ws + alloc((size_t)N * 4));
    int* row_ptr = (int*)(ws + alloc((size_t)(N + 1) * 4));
    int* cursor = (int*)(ws + alloc((size_t)N * 4));
    int* csr = (int*)(ws + alloc((size_t)E * 4));
    float* P1t = (float*)(ws + alloc((size_t)N * HID * 4));
    float* P1b = (float*)(ws + alloc((size_t)N * HID * 4));
    float* S1 = (float*)(ws + alloc((size_t)N * HID * 4));
    float* h = (float*)(ws + alloc((size_t)N * HID * 4));
    // layer-2 buffers reuse layer-1 space (dead after h is computed)
    float* P2t = P1t;
    float* P2b = P1b;
    float* S2 = S1;

    // CSR build (dst is shared by both layers)
    zero_int_kernel<<<(N + 255) / 256, 256, 0, stream>>>(cnt, N);
    hist_kernel<<<(E + 255) / 256, 256, 0, stream>>>(e_dst, cnt, E);
    scan_kernel<<<1, 1024, 0, stream>>>(cnt, row_ptr, cursor, N);
    scatter_kernel<<<(E + 255) / 256, 256, 0, stream>>>(e_src, e_dst, cursor, csr, E);

    dim3 gHID((N + BM - 1) / BM, HID / BN);   // (157, 2)
    dim3 gOUT((N + BM - 1) / BM, OUTD / BN);  // (157, 1)

    // Layer 1: projections (bias folded into dst-part), aggregate, second linear + relu
    gemm_f32<<<gHID, 256, 0, stream>>>(x, N, NODE_DIM, W1a, HID, b1a, nullptr, P1t, HID, 0);
    gemm_f32<<<gHID, 256, 0, stream>>>(x, N, NODE_DIM, W1a + (size_t)NODE_DIM * HID, HID,
                                       nullptr, nullptr, P1b, HID, 0);
    agg_kernel<HID><<<(N + 3) / 4, 256, 0, stream>>>(P1t, P1b, row_ptr, csr, S1, N);
    gemm_f32<<<gHID, 256, 0, stream>>>(S1, N, HID, W1b, HID, b1b, cnt, h, HID, 1);

    // Layer 2
    gemm_f32<<<gOUT, 256, 0, stream>>>(h, N, HID, W2a, OUTD, b2a, nullptr, P2t, OUTD, 0);
    gemm_f32<<<gOUT, 256, 0, stream>>>(h, N, HID, W2a + (size_t)(2 * HID - HID) * OUTD + (size_t)0, OUTD,
                                       nullptr, nullptr, P2b, OUTD, 0);
    agg_kernel<OUTD><<<(N + 3) / 4, 256, 0, stream>>>(P2t, P2b, row_ptr, csr, S2, N);
    gemm_f32<<<gOUT, 256, 0, stream>>>(S2, N, OUTD, W2b, OUTD, b2b, cnt, (float*)d_out, OUTD, 0);
}

// Round 2
// 444.123 us; speedup vs baseline: 1.1001x; 1.1001x over previous
//
#include <hip/hip_runtime.h>
#include <hip/hip_bf16.h>

// GraphEncoder: 2-layer GNN with edge-MLP + scatter-mean.
// Key reformulation:
//   cat(x_dst,x_src)@Wa = (x@Wa_top)[dst] + (x@Wa_bot)[src]
//   mean_agg(relu(pre)@Wb + bb) = mean_agg(relu(pre))@Wb + (cnt>0)*bb
// => per-edge work is just relu(add) + CSR mean aggregation; all GEMMs are N-scale.
// R2: agg edge-loop unrolled x4 (4 independent row-gathers in flight) — the R1
// profile showed agg latency-bound (VALUBusy 18%, BW 3 TB/s, occupancy 63%).

#define N_NODES 20000
#define NODE_DIM 128
#define HID 256
#define OUTD 128

// ---------------- utility kernels ----------------

__global__ void zero_int_kernel(int* __restrict__ p, int n) {
    int i = blockIdx.x * blockDim.x + threadIdx.x;
    if (i < n) p[i] = 0;
}

__global__ void hist_kernel(const int* __restrict__ dst, int* __restrict__ cnt, int E) {
    int e = blockIdx.x * blockDim.x + threadIdx.x;
    if (e < E) atomicAdd(&cnt[dst[e]], 1);
}

// single-block exclusive scan over cnt -> row_ptr (and cursor copy), row_ptr[N]=E
__global__ __launch_bounds__(1024) void scan_kernel(const int* __restrict__ cnt,
                                                    int* __restrict__ row_ptr,
                                                    int* __restrict__ cursor, int N) {
    __shared__ int buf[1024];
    int tid = threadIdx.x;
    int running = 0;
    for (int base = 0; base < N; base += 1024) {
        int i = base + tid;
        int v = (i < N) ? cnt[i] : 0;
        buf[tid] = v;
        __syncthreads();
        for (int off = 1; off < 1024; off <<= 1) {
            int t = (tid >= off) ? buf[tid - off] : 0;
            __syncthreads();
            buf[tid] += t;
            __syncthreads();
        }
        int incl = buf[tid];
        int total = buf[1023];
        if (i < N) {
            int ex = running + incl - v;
            row_ptr[i] = ex;
            cursor[i] = ex;
        }
        running += total;
        __syncthreads();
    }
    if (tid == 0) row_ptr[N] = running;
}

__global__ void scatter_kernel(const int* __restrict__ src, const int* __restrict__ dst,
                               int* __restrict__ cursor, int* __restrict__ csr, int E) {
    int e = blockIdx.x * blockDim.x + threadIdx.x;
    if (e < E) {
        int p = atomicAdd(&cursor[dst[e]], 1);
        csr[p] = src[e];
    }
}

// ---------------- f32 tiled GEMM ----------------
// C[M][Nc] = act(A[M][K] @ B[K][Nc](ldb) + bias * gatemask)
// BM=128, BN=128, BK=16, 256 threads, 8x8 per thread (4+4 split to keep LDS reads 2-way max)

#define BM 128
#define BN 128
#define BK 16

__global__ __launch_bounds__(256) void gemm_f32(
    const float* __restrict__ A, int M, int K,
    const float* __restrict__ B, int ldb,
    const float* __restrict__ bias, const int* __restrict__ gate,
    float* __restrict__ C, int Nc, int relu) {
    __shared__ float As[BK][BM + 4];
    __shared__ float Bs[BK][BN + 4];

    const int tid = threadIdx.x;
    const int ty = tid >> 4;   // 0..15
    const int tx = tid & 15;   // 0..15
    const int m0 = blockIdx.x * BM;
    const int n0 = blockIdx.y * BN;

    float acc[8][8];
#pragma unroll
    for (int i = 0; i < 8; i++)
#pragma unroll
        for (int j = 0; j < 8; j++) acc[i][j] = 0.f;

    for (int kt = 0; kt < K; kt += BK) {
        // A tile: 128 rows x 16 k, transposed into As[k][row]
#pragma unroll
        for (int l = 0; l < 2; l++) {
            int p = tid + l * 256;      // 0..511
            int row = p >> 2;           // 0..127
            int c4 = (p & 3) * 4;       // 0,4,8,12
            int gr = m0 + row;
            float4 v = make_float4(0.f, 0.f, 0.f, 0.f);
            if (gr < M) v = *(const float4*)(A + (size_t)gr * K + kt + c4);
            As[c4 + 0][row] = v.x;
            As[c4 + 1][row] = v.y;
            As[c4 + 2][row] = v.z;
            As[c4 + 3][row] = v.w;
        }
        // B tile: 16 k x 128 cols
#pragma unroll
        for (int l = 0; l < 2; l++) {
            int p = tid + l * 256;
            int kk = p >> 5;            // 0..15
            int n4 = (p & 31) * 4;      // 0..124
            float4 v = *(const float4*)(B + (size_t)(kt + kk) * ldb + n0 + n4);
            *(float4*)&Bs[kk][n4] = v;
        }
        __syncthreads();

#pragma unroll
        for (int k = 0; k < BK; k++) {
            float a[8], b[8];
            *(float4*)&a[0] = *(const float4*)&As[k][ty * 4];
            *(float4*)&a[4] = *(const float4*)&As[k][64 + ty * 4];
            *(float4*)&b[0] = *(const float4*)&Bs[k][tx * 4];
            *(float4*)&b[4] = *(const float4*)&Bs[k][64 + tx * 4];
#pragma unroll
            for (int i = 0; i < 8; i++)
#pragma unroll
                for (int j = 0; j < 8; j++) acc[i][j] += a[i] * b[j];
        }
        __syncthreads();
    }

    // epilogue
    float bv[8];
#pragma unroll
    for (int j = 0; j < 8; j++) {
        int c = n0 + ((j < 4) ? (tx * 4 + j) : (64 + tx * 4 + j - 4));
        bv[j] = bias ? bias[c] : 0.f;
    }
#pragma unroll
    for (int i = 0; i < 8; i++) {
        int r = m0 + ((i < 4) ? (ty * 4 + i) : (64 + ty * 4 + i - 4));
        if (r >= M) continue;
        float g = 1.f;
        if (gate) g = (gate[r] > 0) ? 1.f : 0.f;
        float out[8];
#pragma unroll
        for (int j = 0; j < 8; j++) {
            float v = acc[i][j] + bv[j] * g;
            out[j] = relu ? fmaxf(v, 0.f) : v;
        }
        float* cp = C + (size_t)r * Nc + n0;
        *(float4*)(cp + tx * 4) = *(const float4*)&out[0];
        *(float4*)(cp + 64 + tx * 4) = *(const float4*)&out[4];
    }
}

// ---------------- CSR mean aggregation ----------------
// one wave per node: acc = mean_{e in in(n)} relu(Ptop[n] + Pbot[src_e])
// Edge loop unrolled x4: 4 independent row-gathers in flight per wave.

template <int H>
__global__ __launch_bounds__(256) void agg_kernel(const float* __restrict__ Ptop,
                                                  const float* __restrict__ Pbot,
                                                  const int* __restrict__ row_ptr,
                                                  const int* __restrict__ csr,
                                                  float* __restrict__ S, int N) {
    constexpr int VPL = H / 64;  // 4 (H=256) or 2 (H=128)
    const int wave = threadIdx.x >> 6;
    const int lane = threadIdx.x & 63;
    const int n = blockIdx.x * (blockDim.x >> 6) + wave;
    if (n >= N) return;

    const int begin = row_ptr[n];
    const int end = row_ptr[n + 1];

    float top[VPL], acc[VPL];
    if constexpr (VPL == 4) {
        float4 t = *(const float4*)(Ptop + (size_t)n * H + lane * 4);
        top[0] = t.x; top[1] = t.y; top[2] = t.z; top[3] = t.w;
    } else {
        float2 t = *(const float2*)(Ptop + (size_t)n * H + lane * 2);
        top[0] = t.x; top[1] = t.y;
    }
#pragma unroll
    for (int i = 0; i < VPL; i++) acc[i] = 0.f;

    int e = begin;
    for (; e + 4 <= end; e += 4) {
        int s0 = csr[e + 0];
        int s1 = csr[e + 1];
        int s2 = csr[e + 2];
        int s3 = csr[e + 3];
        if constexpr (VPL == 4) {
            float4 v0 = *(const float4*)(Pbot + (size_t)s0 * H + lane * 4);
            float4 v1 = *(const float4*)(Pbot + (size_t)s1 * H + lane * 4);
            float4 v2 = *(const float4*)(Pbot + (size_t)s2 * H + lane * 4);
            float4 v3 = *(const float4*)(Pbot + (size_t)s3 * H + lane * 4);
            acc[0] += fmaxf(top[0] + v0.x, 0.f) + fmaxf(top[0] + v1.x, 0.f) +
                      fmaxf(top[0] + v2.x, 0.f) + fmaxf(top[0] + v3.x, 0.f);
            acc[1] += fmaxf(top[1] + v0.y, 0.f) + fmaxf(top[1] + v1.y, 0.f) +
                      fmaxf(top[1] + v2.y, 0.f) + fmaxf(top[1] + v3.y, 0.f);
            acc[2] += fmaxf(top[2] + v0.z, 0.f) + fmaxf(top[2] + v1.z, 0.f) +
                      fmaxf(top[2] + v2.z, 0.f) + fmaxf(top[2] + v3.z, 0.f);
            acc[3] += fmaxf(top[3] + v0.w, 0.f) + fmaxf(top[3] + v1.w, 0.f) +
                      fmaxf(top[3] + v2.w, 0.f) + fmaxf(top[3] + v3.w, 0.f);
        } else {
            float2 v0 = *(const float2*)(Pbot + (size_t)s0 * H + lane * 2);
            float2 v1 = *(const float2*)(Pbot + (size_t)s1 * H + lane * 2);
            float2 v2 = *(const float2*)(Pbot + (size_t)s2 * H + lane * 2);
            float2 v3 = *(const float2*)(Pbot + (size_t)s3 * H + lane * 2);
            acc[0] += fmaxf(top[0] + v0.x, 0.f) + fmaxf(top[0] + v1.x, 0.f) +
                      fmaxf(top[0] + v2.x, 0.f) + fmaxf(top[0] + v3.x, 0.f);
            acc[1] += fmaxf(top[1] + v0.y, 0.f) + fmaxf(top[1] + v1.y, 0.f) +
                      fmaxf(top[1] + v2.y, 0.f) + fmaxf(top[1] + v3.y, 0.f);
        }
    }
    for (; e < end; e++) {
        int s = csr[e];
        if constexpr (VPL == 4) {
            float4 v = *(const float4*)(Pbot + (size_t)s * H + lane * 4);
            acc[0] += fmaxf(top[0] + v.x, 0.f);
            acc[1] += fmaxf(top[1] + v.y, 0.f);
            acc[2] += fmaxf(top[2] + v.z, 0.f);
            acc[3] += fmaxf(top[3] + v.w, 0.f);
        } else {
            float2 v = *(const float2*)(Pbot + (size_t)s * H + lane * 2);
            acc[0] += fmaxf(top[0] + v.x, 0.f);
            acc[1] += fmaxf(top[1] + v.y, 0.f);
        }
    }

    float inv = (end > begin) ? 1.f / (float)(end - begin) : 0.f;
    if constexpr (VPL == 4) {
        float4 o = make_float4(acc[0] * inv, acc[1] * inv, acc[2] * inv, acc[3] * inv);
        *(float4*)(S + (size_t)n * H + lane * 4) = o;
    } else {
        float2 o = make_float2(acc[0] * inv, acc[1] * inv);
        *(float2*)(S + (size_t)n * H + lane * 2) = o;
    }
}

// ---------------- launch ----------------

extern "C" void kernel_launch(void* const* d_in, const int* in_sizes, int n_in,
                              void* d_out, int out_size, void* d_ws, size_t ws_size,
                              hipStream_t stream) {
    const int N = in_sizes[0] / NODE_DIM;  // 20000
    const int E = in_sizes[1] / 2;         // 640000

    const float* x = (const float*)d_in[0];
    const int* ei = (const int*)d_in[1];
    const int* e_src = ei;
    const int* e_dst = ei + E;
    const float* W1a = (const float*)d_in[2];
    const float* b1a = (const float*)d_in[3];
    const float* W1b = (const float*)d_in[4];
    const float* b1b = (const float*)d_in[5];
    const float* W2a = (const float*)d_in[6];
    const float* b2a = (const float*)d_in[7];
    const float* W2b = (const float*)d_in[8];
    const float* b2b = (const float*)d_in[9];

    char* ws = (char*)d_ws;
    size_t off = 0;
    auto alloc = [&](size_t bytes) {
        size_t o = off;
        off += (bytes + 255) & ~(size_t)255;
        return o;
    };
    int* cnt = (int*)(ws + alloc((size_t)N * 4));
    int* row_ptr = (int*)(ws + alloc((size_t)(N + 1) * 4));
    int* cursor = (int*)(ws + alloc((size_t)N * 4));
    int* csr = (int*)(ws + alloc((size_t)E * 4));
    float* P1t = (float*)(ws + alloc((size_t)N * HID * 4));
    float* P1b = (float*)(ws + alloc((size_t)N * HID * 4));
    float* S1 = (float*)(ws + alloc((size_t)N * HID * 4));
    float* h = (float*)(ws + alloc((size_t)N * HID * 4));
    // layer-2 buffers reuse layer-1 space (dead after h is computed)
    float* P2t = P1t;
    float* P2b = P1b;
    float* S2 = S1;

    // CSR build (dst is shared by both layers)
    zero_int_kernel<<<(N + 255) / 256, 256, 0, stream>>>(cnt, N);
    hist_kernel<<<(E + 255) / 256, 256, 0, stream>>>(e_dst, cnt, E);
    scan_kernel<<<1, 1024, 0, stream>>>(cnt, row_ptr, cursor, N);
    scatter_kernel<<<(E + 255) / 256, 256, 0, stream>>>(e_src, e_dst, cursor, csr, E);

    dim3 gHID((N + BM - 1) / BM, HID / BN);   // (157, 2)
    dim3 gOUT((N + BM - 1) / BM, OUTD / BN);  // (157, 1)

    // Layer 1: projections (bias folded into dst-part), aggregate, second linear + relu
    gemm_f32<<<gHID, 256, 0, stream>>>(x, N, NODE_DIM, W1a, HID, b1a, nullptr, P1t, HID, 0);
    gemm_f32<<<gHID, 256, 0, stream>>>(x, N, NODE_DIM, W1a + (size_t)NODE_DIM * HID, HID,
                                       nullptr, nullptr, P1b, HID, 0);
    agg_kernel<HID><<<(N + 3) / 4, 256, 0, stream>>>(P1t, P1b, row_ptr, csr, S1, N);
    gemm_f32<<<gHID, 256, 0, stream>>>(S1, N, HID, W1b, HID, b1b, cnt, h, HID, 1);

    // Layer 2
    gemm_f32<<<gOUT, 256, 0, stream>>>(h, N, HID, W2a, OUTD, b2a, nullptr, P2t, OUTD, 0);
    gemm_f32<<<gOUT, 256, 0, stream>>>(h, N, HID, W2a + (size_t)HID * OUTD, OUTD,
                                       nullptr, nullptr, P2b, OUTD, 0);
    agg_kernel<OUTD><<<(N + 3) / 4, 256, 0, stream>>>(P2t, P2b, row_ptr, csr, S2, N);
    gemm_f32<<<gOUT, 256, 0, stream>>>(S2, N, OUTD, W2b, OUTD, b2b, cnt, (float*)d_out, OUTD, 0);
}

// Round 4
// 314.790 us; speedup vs baseline: 1.5521x; 1.4109x over previous
//
#include <hip/hip_runtime.h>
#include <hip/hip_bf16.h>

// GraphEncoder: 2-layer GNN, edge-MLP + scatter-mean.
//   cat(x_dst,x_src)@Wa = (x@Wa_top)[dst] + (x@Wa_bot)[src]
//   mean_agg(relu(pre)@Wb + bb) = mean_agg(relu(pre))@Wb + (cnt>0)*bb
// R4: bf16 MFMA 3-pass (hi/lo split) GEMMs; fixed A-staging (full 32 cols) and
//     direct 16B-aligned LDS vector loads (80B rows -> 2-way bank alias = free).

#define NODE_DIM 128
#define HID 256
#define OUTD 128

typedef __attribute__((ext_vector_type(8))) short bf16x8;
typedef __attribute__((ext_vector_type(4))) float f32x4;

__device__ __forceinline__ float bf2f(ushort u) {
    return __uint_as_float(((unsigned)u) << 16);
}
__device__ __forceinline__ ushort f2bf_rne(float x) {
    unsigned u = __float_as_uint(x);
    unsigned r = u + 0x7fffu + ((u >> 16) & 1u);
    return (ushort)(r >> 16);
}
__device__ __forceinline__ void split2(float x, ushort& hi, ushort& lo) {
    hi = f2bf_rne(x);
    float hf = __uint_as_float(((unsigned)hi) << 16);
    lo = f2bf_rne(x - hf);
}

// ---------------- utility kernels ----------------

__global__ void zero_int_kernel(int* __restrict__ p, int n) {
    int i = blockIdx.x * blockDim.x + threadIdx.x;
    if (i < n) p[i] = 0;
}

__global__ void hist_kernel(const int* __restrict__ dst, int* __restrict__ cnt, int E) {
    int e = blockIdx.x * blockDim.x + threadIdx.x;
    if (e < E) atomicAdd(&cnt[dst[e]], 1);
}

__global__ __launch_bounds__(1024) void scan_kernel(const int* __restrict__ cnt,
                                                    int* __restrict__ row_ptr,
                                                    int* __restrict__ cursor, int N) {
    __shared__ int buf[1024];
    int tid = threadIdx.x;
    int running = 0;
    for (int base = 0; base < N; base += 1024) {
        int i = base + tid;
        int v = (i < N) ? cnt[i] : 0;
        buf[tid] = v;
        __syncthreads();
        for (int off = 1; off < 1024; off <<= 1) {
            int t = (tid >= off) ? buf[tid - off] : 0;
            __syncthreads();
            buf[tid] += t;
            __syncthreads();
        }
        int incl = buf[tid];
        int total = buf[1023];
        if (i < N) {
            int ex = running + incl - v;
            row_ptr[i] = ex;
            cursor[i] = ex;
        }
        running += total;
        __syncthreads();
    }
    if (tid == 0) row_ptr[N] = running;
}

__global__ void scatter_kernel(const int* __restrict__ src, const int* __restrict__ dst,
                               int* __restrict__ cursor, int* __restrict__ csr, int E) {
    int e = blockIdx.x * blockDim.x + threadIdx.x;
    if (e < E) {
        int p = atomicAdd(&cursor[dst[e]], 1);
        csr[p] = src[e];
    }
}

// split f32 array -> hi/lo bf16 (4 elems/thread)
__global__ void split_kernel(const float* __restrict__ x, ushort* __restrict__ hi,
                             ushort* __restrict__ lo, int n4) {
    int i = blockIdx.x * blockDim.x + threadIdx.x;
    if (i >= n4) return;
    float4 v = ((const float4*)x)[i];
    ushort4 h, l;
    split2(v.x, h.x, l.x);
    split2(v.y, h.y, l.y);
    split2(v.z, h.z, l.z);
    split2(v.w, h.w, l.w);
    ((ushort4*)hi)[i] = h;
    ((ushort4*)lo)[i] = l;
}

// W[(k0+k)*ldw + n] -> T{hi,lo}[n*K + k]   (transpose + split)
__global__ void tsplit_kernel(const float* __restrict__ W, int k0, int K, int Nc, int ldw,
                              ushort* __restrict__ Thi, ushort* __restrict__ Tlo) {
    int i = blockIdx.x * blockDim.x + threadIdx.x;
    if (i >= Nc * K) return;
    int n = i / K, k = i - n * K;
    float v = W[(size_t)(k0 + k) * ldw + n];
    ushort h, l;
    split2(v, h, l);
    Thi[(size_t)n * K + k] = h;
    Tlo[(size_t)n * K + k] = l;
}

// ---------------- bf16 3-pass MFMA GEMM ----------------
// C[M][Nc] = act(A @ B + bias*gate), A[M][K] as hi/lo bf16, B transposed [Nc][K] hi/lo.
// Tile: BM=128, BN=64, BK=32; 256 threads = 4 waves (2m x 2n), wave tile 64x32.
// LDS rows 40 ushorts (80B); all vector accesses 16B-aligned; ds_read_b128 2-way alias.
// MODE: 0 = f32 out, 1 = bf16 out, 2 = hi/lo out.

#define GBM 128
#define GBN 64
#define GBK 32
#define LDSW 40

template <int MODE>
__global__ __launch_bounds__(256) void gemm_bf3(
    const ushort* __restrict__ Ahi, const ushort* __restrict__ Alo, int M, int K,
    const ushort* __restrict__ BThi, const ushort* __restrict__ BTlo,
    const float* __restrict__ bias, const int* __restrict__ gate, int relu,
    float* __restrict__ Cf, ushort* __restrict__ Chi, ushort* __restrict__ Clo, int Nc) {
    __shared__ ushort sAh[GBM * LDSW], sAl[GBM * LDSW];
    __shared__ ushort sBh[GBN * LDSW], sBl[GBN * LDSW];

    const int tid = threadIdx.x;
    const int lane = tid & 63;
    const int w = tid >> 6;
    const int wm = w >> 1, wn = w & 1;
    const int r16 = lane & 15, kg = lane >> 4;
    const int m0 = blockIdx.x * GBM;
    const int n0 = blockIdx.y * GBN;

    // staging coords
    const int arow = tid >> 1, ahalf = tid & 1;   // A: 2 thr/row, 16 ushorts (2x int4) each
    const int brow = tid >> 2, bchunk = tid & 3;  // B: 4 thr/row, 8 ushorts (1x int4) each

    f32x4 acc[4][2];
#pragma unroll
    for (int i = 0; i < 4; i++)
#pragma unroll
        for (int j = 0; j < 2; j++) acc[i][j] = (f32x4)0.f;

    for (int kt = 0; kt < K; kt += GBK) {
        // stage A (128 rows x 32 cols, hi+lo)
        {
            const int gr = m0 + arow;
            int4 h0 = make_int4(0, 0, 0, 0), h1 = h0, l0 = h0, l1 = h0;
            if (gr < M) {
                const size_t go = (size_t)gr * K + kt + ahalf * 16;
                h0 = *(const int4*)(Ahi + go);
                h1 = *(const int4*)(Ahi + go + 8);
                l0 = *(const int4*)(Alo + go);
                l1 = *(const int4*)(Alo + go + 8);
            }
            ushort* dh = sAh + arow * LDSW + ahalf * 16;
            ushort* dl = sAl + arow * LDSW + ahalf * 16;
            *(int4*)(dh) = h0;
            *(int4*)(dh + 8) = h1;
            *(int4*)(dl) = l0;
            *(int4*)(dl + 8) = l1;
        }
        // stage B (64 rows x 32 cols, hi+lo)
        {
            const size_t go = (size_t)(n0 + brow) * K + kt + bchunk * 8;
            ushort* dh = sBh + brow * LDSW + bchunk * 8;
            ushort* dl = sBl + brow * LDSW + bchunk * 8;
            *(int4*)(dh) = *(const int4*)(BThi + go);
            *(int4*)(dl) = *(const int4*)(BTlo + go);
        }
        __syncthreads();

        bf16x8 ah[4], al[4], bh[2], bl[2];
#pragma unroll
        for (int mi = 0; mi < 4; mi++) {
            const int row = wm * 64 + mi * 16 + r16;
            ah[mi] = *(const bf16x8*)(sAh + row * LDSW + kg * 8);
            al[mi] = *(const bf16x8*)(sAl + row * LDSW + kg * 8);
        }
#pragma unroll
        for (int ni = 0; ni < 2; ni++) {
            const int row = wn * 32 + ni * 16 + r16;
            bh[ni] = *(const bf16x8*)(sBh + row * LDSW + kg * 8);
            bl[ni] = *(const bf16x8*)(sBl + row * LDSW + kg * 8);
        }
#pragma unroll
        for (int mi = 0; mi < 4; mi++)
#pragma unroll
            for (int ni = 0; ni < 2; ni++) {
                acc[mi][ni] = __builtin_amdgcn_mfma_f32_16x16x32_bf16(ah[mi], bh[ni], acc[mi][ni], 0, 0, 0);
                acc[mi][ni] = __builtin_amdgcn_mfma_f32_16x16x32_bf16(ah[mi], bl[ni], acc[mi][ni], 0, 0, 0);
                acc[mi][ni] = __builtin_amdgcn_mfma_f32_16x16x32_bf16(al[mi], bh[ni], acc[mi][ni], 0, 0, 0);
            }
        __syncthreads();
    }

    // epilogue: C/D mapping col=lane&15, row=(lane>>4)*4+reg  [m89-verified]
#pragma unroll
    for (int ni = 0; ni < 2; ni++) {
        const int col = n0 + wn * 32 + ni * 16 + r16;
        const float bv = bias ? bias[col] : 0.f;
#pragma unroll
        for (int mi = 0; mi < 4; mi++) {
#pragma unroll
            for (int r = 0; r < 4; r++) {
                const int row = m0 + wm * 64 + mi * 16 + kg * 4 + r;
                if (row >= M) continue;
                float g = 1.f;
                if (gate) g = (gate[row] > 0) ? 1.f : 0.f;
                float v = acc[mi][ni][r] + bv * g;
                if (relu) v = fmaxf(v, 0.f);
                const size_t o = (size_t)row * Nc + col;
                if constexpr (MODE == 0) {
                    Cf[o] = v;
                } else if constexpr (MODE == 1) {
                    Chi[o] = f2bf_rne(v);
                } else {
                    ushort h, l;
                    split2(v, h, l);
                    Chi[o] = h;
                    Clo[o] = l;
                }
            }
        }
    }
}

// ---------------- CSR mean aggregation ----------------
// one wave per node: S = mean_e relu(Ptop[n] (f32) + Pbot[src_e] (bf16)); out hi/lo bf16.

template <int H>
__global__ __launch_bounds__(256) void agg_kernel(const float* __restrict__ Ptop,
                                                  const ushort* __restrict__ Pbot,
                                                  const int* __restrict__ row_ptr,
                                                  const int* __restrict__ csr,
                                                  ushort* __restrict__ Shi,
                                                  ushort* __restrict__ Slo, int N) {
    constexpr int VPL = H / 64;  // 4 or 2
    const int wave = threadIdx.x >> 6;
    const int lane = threadIdx.x & 63;
    const int n = blockIdx.x * (blockDim.x >> 6) + wave;
    if (n >= N) return;

    const int begin = row_ptr[n];
    const int end = row_ptr[n + 1];

    float top[VPL], acc[VPL];
    if constexpr (VPL == 4) {
        float4 t = *(const float4*)(Ptop + (size_t)n * H + lane * 4);
        top[0] = t.x; top[1] = t.y; top[2] = t.z; top[3] = t.w;
    } else {
        float2 t = *(const float2*)(Ptop + (size_t)n * H + lane * 2);
        top[0] = t.x; top[1] = t.y;
    }
#pragma unroll
    for (int i = 0; i < VPL; i++) acc[i] = 0.f;

    int e = begin;
    for (; e + 8 <= end; e += 8) {
        int idx[8];
#pragma unroll
        for (int j = 0; j < 8; j++) idx[j] = csr[e + j];
        if constexpr (VPL == 4) {
            ushort4 v[8];
#pragma unroll
            for (int j = 0; j < 8; j++)
                v[j] = *(const ushort4*)(Pbot + (size_t)idx[j] * H + lane * 4);
#pragma unroll
            for (int j = 0; j < 8; j++) {
                acc[0] += fmaxf(top[0] + bf2f(v[j].x), 0.f);
                acc[1] += fmaxf(top[1] + bf2f(v[j].y), 0.f);
                acc[2] += fmaxf(top[2] + bf2f(v[j].z), 0.f);
                acc[3] += fmaxf(top[3] + bf2f(v[j].w), 0.f);
            }
        } else {
            ushort2 v[8];
#pragma unroll
            for (int j = 0; j < 8; j++)
                v[j] = *(const ushort2*)(Pbot + (size_t)idx[j] * H + lane * 2);
#pragma unroll
            for (int j = 0; j < 8; j++) {
                acc[0] += fmaxf(top[0] + bf2f(v[j].x), 0.f);
                acc[1] += fmaxf(top[1] + bf2f(v[j].y), 0.f);
            }
        }
    }
    for (; e < end; e++) {
        int s = csr[e];
        if constexpr (VPL == 4) {
            ushort4 v = *(const ushort4*)(Pbot + (size_t)s * H + lane * 4);
            acc[0] += fmaxf(top[0] + bf2f(v.x), 0.f);
            acc[1] += fmaxf(top[1] + bf2f(v.y), 0.f);
            acc[2] += fmaxf(top[2] + bf2f(v.z), 0.f);
            acc[3] += fmaxf(top[3] + bf2f(v.w), 0.f);
        } else {
            ushort2 v = *(const ushort2*)(Pbot + (size_t)s * H + lane * 2);
            acc[0] += fmaxf(top[0] + bf2f(v.x), 0.f);
            acc[1] += fmaxf(top[1] + bf2f(v.y), 0.f);
        }
    }

    const float inv = (end > begin) ? 1.f / (float)(end - begin) : 0.f;
    if constexpr (VPL == 4) {
        ushort4 h, l;
        split2(acc[0] * inv, h.x, l.x);
        split2(acc[1] * inv, h.y, l.y);
        split2(acc[2] * inv, h.z, l.z);
        split2(acc[3] * inv, h.w, l.w);
        *(ushort4*)(Shi + (size_t)n * H + lane * 4) = h;
        *(ushort4*)(Slo + (size_t)n * H + lane * 4) = l;
    } else {
        ushort2 h, l;
        split2(acc[0] * inv, h.x, l.x);
        split2(acc[1] * inv, h.y, l.y);
        *(ushort2*)(Shi + (size_t)n * H + lane * 2) = h;
        *(ushort2*)(Slo + (size_t)n * H + lane * 2) = l;
    }
}

// ---------------- launch ----------------

extern "C" void kernel_launch(void* const* d_in, const int* in_sizes, int n_in,
                              void* d_out, int out_size, void* d_ws, size_t ws_size,
                              hipStream_t stream) {
    const int N = in_sizes[0] / NODE_DIM;  // 20000
    const int E = in_sizes[1] / 2;         // 640000

    const float* x = (const float*)d_in[0];
    const int* ei = (const int*)d_in[1];
    const int* e_src = ei;
    const int* e_dst = ei + E;
    const float* W1a = (const float*)d_in[2];
    const float* b1a = (const float*)d_in[3];
    const float* W1b = (const float*)d_in[4];
    const float* b1b = (const float*)d_in[5];
    const float* W2a = (const float*)d_in[6];
    const float* b2a = (const float*)d_in[7];
    const float* W2b = (const float*)d_in[8];
    const float* b2b = (const float*)d_in[9];

    char* ws = (char*)d_ws;
    size_t off = 0;
    auto alloc = [&](size_t bytes) {
        size_t o = off;
        off += (bytes + 255) & ~(size_t)255;
        return o;
    };
    int* cnt = (int*)(ws + alloc((size_t)N * 4));
    int* row_ptr = (int*)(ws + alloc((size_t)(N + 1) * 4));
    int* cursor = (int*)(ws + alloc((size_t)N * 4));
    int* csr = (int*)(ws + alloc((size_t)E * 4));
    ushort* x_hi = (ushort*)(ws + alloc((size_t)N * NODE_DIM * 2));
    ushort* x_lo = (ushort*)(ws + alloc((size_t)N * NODE_DIM * 2));
    // transposed/split weights
    ushort* T1at_h = (ushort*)(ws + alloc((size_t)HID * NODE_DIM * 2));
    ushort* T1at_l = (ushort*)(ws + alloc((size_t)HID * NODE_DIM * 2));
    ushort* T1ab_h = (ushort*)(ws + alloc((size_t)HID * NODE_DIM * 2));
    ushort* T1ab_l = (ushort*)(ws + alloc((size_t)HID * NODE_DIM * 2));
    ushort* T1b_h = (ushort*)(ws + alloc((size_t)HID * HID * 2));
    ushort* T1b_l = (ushort*)(ws + alloc((size_t)HID * HID * 2));
    ushort* T2at_h = (ushort*)(ws + alloc((size_t)OUTD * HID * 2));
    ushort* T2at_l = (ushort*)(ws + alloc((size_t)OUTD * HID * 2));
    ushort* T2ab_h = (ushort*)(ws + alloc((size_t)OUTD * HID * 2));
    ushort* T2ab_l = (ushort*)(ws + alloc((size_t)OUTD * HID * 2));
    ushort* T2b_h = (ushort*)(ws + alloc((size_t)OUTD * OUTD * 2));
    ushort* T2b_l = (ushort*)(ws + alloc((size_t)OUTD * OUTD * 2));
    // activations
    float* P1t = (float*)(ws + alloc((size_t)N * HID * 4));
    ushort* P1b = (ushort*)(ws + alloc((size_t)N * HID * 2));
    ushort* S1h = (ushort*)(ws + alloc((size_t)N * HID * 2));
    ushort* S1l = (ushort*)(ws + alloc((size_t)N * HID * 2));
    ushort* h_hi = (ushort*)(ws + alloc((size_t)N * HID * 2));
    ushort* h_lo = (ushort*)(ws + alloc((size_t)N * HID * 2));
    // layer-2 reuse
    float* P2t = P1t;
    ushort* P2b = P1b;
    ushort* S2h = S1h;
    ushort* S2l = S1l;

    // CSR build
    zero_int_kernel<<<(N + 255) / 256, 256, 0, stream>>>(cnt, N);
    hist_kernel<<<(E + 255) / 256, 256, 0, stream>>>(e_dst, cnt, E);
    scan_kernel<<<1, 1024, 0, stream>>>(cnt, row_ptr, cursor, N);
    scatter_kernel<<<(E + 255) / 256, 256, 0, stream>>>(e_src, e_dst, cursor, csr, E);

    // splits
    split_kernel<<<((N * NODE_DIM / 4) + 255) / 256, 256, 0, stream>>>(x, x_hi, x_lo, N * NODE_DIM / 4);
    tsplit_kernel<<<(HID * NODE_DIM + 255) / 256, 256, 0, stream>>>(W1a, 0, NODE_DIM, HID, HID, T1at_h, T1at_l);
    tsplit_kernel<<<(HID * NODE_DIM + 255) / 256, 256, 0, stream>>>(W1a, NODE_DIM, NODE_DIM, HID, HID, T1ab_h, T1ab_l);
    tsplit_kernel<<<(HID * HID + 255) / 256, 256, 0, stream>>>(W1b, 0, HID, HID, HID, T1b_h, T1b_l);
    tsplit_kernel<<<(OUTD * HID + 255) / 256, 256, 0, stream>>>(W2a, 0, HID, OUTD, OUTD, T2at_h, T2at_l);
    tsplit_kernel<<<(OUTD * HID + 255) / 256, 256, 0, stream>>>(W2a, HID, HID, OUTD, OUTD, T2ab_h, T2ab_l);
    tsplit_kernel<<<(OUTD * OUTD + 255) / 256, 256, 0, stream>>>(W2b, 0, OUTD, OUTD, OUTD, T2b_h, T2b_l);

    const int MT = (N + GBM - 1) / GBM;  // 157
    dim3 gH(MT, HID / GBN);              // (157,4)
    dim3 gO(MT, OUTD / GBN);             // (157,2)

    // Layer 1
    gemm_bf3<0><<<gH, 256, 0, stream>>>(x_hi, x_lo, N, NODE_DIM, T1at_h, T1at_l,
                                        b1a, nullptr, 0, P1t, nullptr, nullptr, HID);
    gemm_bf3<1><<<gH, 256, 0, stream>>>(x_hi, x_lo, N, NODE_DIM, T1ab_h, T1ab_l,
                                        nullptr, nullptr, 0, nullptr, P1b, nullptr, HID);
    agg_kernel<HID><<<(N + 3) / 4, 256, 0, stream>>>(P1t, P1b, row_ptr, csr, S1h, S1l, N);
    gemm_bf3<2><<<gH, 256, 0, stream>>>(S1h, S1l, N, HID, T1b_h, T1b_l,
                                        b1b, cnt, 1, nullptr, h_hi, h_lo, HID);

    // Layer 2
    gemm_bf3<0><<<gO, 256, 0, stream>>>(h_hi, h_lo, N, HID, T2at_h, T2at_l,
                                        b2a, nullptr, 0, P2t, nullptr, nullptr, OUTD);
    gemm_bf3<1><<<gO, 256, 0, stream>>>(h_hi, h_lo, N, HID, T2ab_h, T2ab_l,
                                        nullptr, nullptr, 0, nullptr, P2b, nullptr, OUTD);
    agg_kernel<OUTD><<<(N + 3) / 4, 256, 0, stream>>>(P2t, P2b, row_ptr, csr, S2h, S2l, N);
    gemm_bf3<0><<<gO, 256, 0, stream>>>(S2h, S2l, N, OUTD, T2b_h, T2b_l,
                                        b2b, cnt, 0, (float*)d_out, nullptr, nullptr, OUTD);
}

// Round 5
// 295.797 us; speedup vs baseline: 1.6517x; 1.0642x over previous
//
#include <hip/hip_runtime.h>
#include <hip/hip_bf16.h>

// GraphEncoder: 2-layer GNN, edge-MLP + scatter-mean.
//   cat(x_dst,x_src)@Wa = (x@Wa_top)[dst] + (x@Wa_bot)[src]
//   mean_agg(relu(pre)@Wb + bb) = mean_agg(relu(pre))@Wb + (cnt>0)*bb
// R5: (1) agg: 4 waves/node (strided edge split + LDS combine) — attack latency;
//     (2) merged projection GEMMs (dual epilogue f32|bf16), 6 -> 4 GEMM dispatches;
//     (3) shuffle-based scan (was ~30 barriers/chunk on one CU).

#define NODE_DIM 128
#define HID 256
#define OUTD 128

typedef __attribute__((ext_vector_type(8))) short bf16x8;
typedef __attribute__((ext_vector_type(4))) float f32x4;

__device__ __forceinline__ float bf2f(ushort u) {
    return __uint_as_float(((unsigned)u) << 16);
}
__device__ __forceinline__ ushort f2bf_rne(float x) {
    unsigned u = __float_as_uint(x);
    unsigned r = u + 0x7fffu + ((u >> 16) & 1u);
    return (ushort)(r >> 16);
}
__device__ __forceinline__ void split2(float x, ushort& hi, ushort& lo) {
    hi = f2bf_rne(x);
    float hf = __uint_as_float(((unsigned)hi) << 16);
    lo = f2bf_rne(x - hf);
}

// ---------------- utility kernels ----------------

__global__ void zero_int_kernel(int* __restrict__ p, int n) {
    int i = blockIdx.x * blockDim.x + threadIdx.x;
    if (i < n) p[i] = 0;
}

__global__ void hist_kernel(const int* __restrict__ dst, int* __restrict__ cnt, int E) {
    int e = blockIdx.x * blockDim.x + threadIdx.x;
    if (e < E) atomicAdd(&cnt[dst[e]], 1);
}

// exclusive scan over cnt -> row_ptr + cursor; single block, shuffle-based
__global__ __launch_bounds__(1024) void scan_kernel(const int* __restrict__ cnt,
                                                    int* __restrict__ row_ptr,
                                                    int* __restrict__ cursor, int N) {
    __shared__ int wsum[16];
    const int tid = threadIdx.x;
    const int lane = tid & 63;
    const int wv = tid >> 6;
    int running = 0;
    for (int base = 0; base < N; base += 1024) {
        const int i = base + tid;
        const int v = (i < N) ? cnt[i] : 0;
        int x = v;
#pragma unroll
        for (int off = 1; off < 64; off <<= 1) {
            int t = __shfl_up(x, off, 64);
            if (lane >= off) x += t;
        }
        if (lane == 63) wsum[wv] = x;
        __syncthreads();
        if (wv == 0) {
            int s = (lane < 16) ? wsum[lane] : 0;
#pragma unroll
            for (int off = 1; off < 16; off <<= 1) {
                int t = __shfl_up(s, off, 64);
                if (lane >= off) s += t;
            }
            if (lane < 16) wsum[lane] = s;
        }
        __syncthreads();
        const int woff = (wv > 0) ? wsum[wv - 1] : 0;
        const int total = wsum[15];
        if (i < N) {
            int ex = running + woff + x - v;
            row_ptr[i] = ex;
            cursor[i] = ex;
        }
        running += total;
        __syncthreads();
    }
    if (tid == 0) row_ptr[N] = running;
}

__global__ void scatter_kernel(const int* __restrict__ src, const int* __restrict__ dst,
                               int* __restrict__ cursor, int* __restrict__ csr, int E) {
    int e = blockIdx.x * blockDim.x + threadIdx.x;
    if (e < E) {
        int p = atomicAdd(&cursor[dst[e]], 1);
        csr[p] = src[e];
    }
}

// split f32 array -> hi/lo bf16 (4 elems/thread)
__global__ void split_kernel(const float* __restrict__ x, ushort* __restrict__ hi,
                             ushort* __restrict__ lo, int n4) {
    int i = blockIdx.x * blockDim.x + threadIdx.x;
    if (i >= n4) return;
    float4 v = ((const float4*)x)[i];
    ushort4 h, l;
    split2(v.x, h.x, l.x);
    split2(v.y, h.y, l.y);
    split2(v.z, h.z, l.z);
    split2(v.w, h.w, l.w);
    ((ushort4*)hi)[i] = h;
    ((ushort4*)lo)[i] = l;
}

// W[(k0+k)*ldw + n] -> T{hi,lo}[n*K + k]   (transpose + split)
__global__ void tsplit_kernel(const float* __restrict__ W, int k0, int K, int Nc, int ldw,
                              ushort* __restrict__ Thi, ushort* __restrict__ Tlo) {
    int i = blockIdx.x * blockDim.x + threadIdx.x;
    if (i >= Nc * K) return;
    int n = i / K, k = i - n * K;
    float v = W[(size_t)(k0 + k) * ldw + n];
    ushort h, l;
    split2(v, h, l);
    Thi[(size_t)n * K + k] = h;
    Tlo[(size_t)n * K + k] = l;
}

// ---------------- bf16 3-pass MFMA GEMM ----------------
// A[M][K] hi/lo bf16; B transposed [Nc][K] hi/lo. Tile BM=128,BN=64,BK=32; 4 waves.
// MODE 0: f32 out (+bias, +gate, +relu). MODE 1: dual — col<nsplit -> f32+bias (ld
// nsplit); col>=nsplit -> bf16 (ld Nc-nsplit). MODE 2: hi/lo bf16 out (+bias,+gate,+relu).

#define GBM 128
#define GBN 64
#define GBK 32
#define LDSW 40

template <int MODE>
__global__ __launch_bounds__(256) void gemm_bf3(
    const ushort* __restrict__ Ahi, const ushort* __restrict__ Alo, int M, int K,
    const ushort* __restrict__ BThi, const ushort* __restrict__ BTlo,
    const float* __restrict__ bias, const int* __restrict__ gate, int relu,
    float* __restrict__ Cf, ushort* __restrict__ Chi, ushort* __restrict__ Clo,
    int Nc, int nsplit) {
    __shared__ ushort sAh[GBM * LDSW], sAl[GBM * LDSW];
    __shared__ ushort sBh[GBN * LDSW], sBl[GBN * LDSW];

    const int tid = threadIdx.x;
    const int lane = tid & 63;
    const int w = tid >> 6;
    const int wm = w >> 1, wn = w & 1;
    const int r16 = lane & 15, kg = lane >> 4;
    const int m0 = blockIdx.x * GBM;
    const int n0 = blockIdx.y * GBN;

    const int arow = tid >> 1, ahalf = tid & 1;   // A: 2 thr/row, 16 ushorts (2x int4)
    const int brow = tid >> 2, bchunk = tid & 3;  // B: 4 thr/row, 8 ushorts (1x int4)

    f32x4 acc[4][2];
#pragma unroll
    for (int i = 0; i < 4; i++)
#pragma unroll
        for (int j = 0; j < 2; j++) acc[i][j] = (f32x4)0.f;

    for (int kt = 0; kt < K; kt += GBK) {
        {
            const int gr = m0 + arow;
            int4 h0 = make_int4(0, 0, 0, 0), h1 = h0, l0 = h0, l1 = h0;
            if (gr < M) {
                const size_t go = (size_t)gr * K + kt + ahalf * 16;
                h0 = *(const int4*)(Ahi + go);
                h1 = *(const int4*)(Ahi + go + 8);
                l0 = *(const int4*)(Alo + go);
                l1 = *(const int4*)(Alo + go + 8);
            }
            ushort* dh = sAh + arow * LDSW + ahalf * 16;
            ushort* dl = sAl + arow * LDSW + ahalf * 16;
            *(int4*)(dh) = h0;
            *(int4*)(dh + 8) = h1;
            *(int4*)(dl) = l0;
            *(int4*)(dl + 8) = l1;
        }
        {
            const size_t go = (size_t)(n0 + brow) * K + kt + bchunk * 8;
            ushort* dh = sBh + brow * LDSW + bchunk * 8;
            ushort* dl = sBl + brow * LDSW + bchunk * 8;
            *(int4*)(dh) = *(const int4*)(BThi + go);
            *(int4*)(dl) = *(const int4*)(BTlo + go);
        }
        __syncthreads();

        bf16x8 ah[4], al[4], bh[2], bl[2];
#pragma unroll
        for (int mi = 0; mi < 4; mi++) {
            const int row = wm * 64 + mi * 16 + r16;
            ah[mi] = *(const bf16x8*)(sAh + row * LDSW + kg * 8);
            al[mi] = *(const bf16x8*)(sAl + row * LDSW + kg * 8);
        }
#pragma unroll
        for (int ni = 0; ni < 2; ni++) {
            const int row = wn * 32 + ni * 16 + r16;
            bh[ni] = *(const bf16x8*)(sBh + row * LDSW + kg * 8);
            bl[ni] = *(const bf16x8*)(sBl + row * LDSW + kg * 8);
        }
#pragma unroll
        for (int mi = 0; mi < 4; mi++)
#pragma unroll
            for (int ni = 0; ni < 2; ni++) {
                acc[mi][ni] = __builtin_amdgcn_mfma_f32_16x16x32_bf16(ah[mi], bh[ni], acc[mi][ni], 0, 0, 0);
                acc[mi][ni] = __builtin_amdgcn_mfma_f32_16x16x32_bf16(ah[mi], bl[ni], acc[mi][ni], 0, 0, 0);
                acc[mi][ni] = __builtin_amdgcn_mfma_f32_16x16x32_bf16(al[mi], bh[ni], acc[mi][ni], 0, 0, 0);
            }
        __syncthreads();
    }

    // epilogue: C/D mapping col=lane&15, row=(lane>>4)*4+reg  [m89-verified]
#pragma unroll
    for (int ni = 0; ni < 2; ni++) {
        const int col = n0 + wn * 32 + ni * 16 + r16;
        float bv = 0.f;
        if constexpr (MODE == 1) {
            bv = (col < nsplit && bias) ? bias[col] : 0.f;
        } else {
            bv = bias ? bias[col] : 0.f;
        }
#pragma unroll
        for (int mi = 0; mi < 4; mi++) {
#pragma unroll
            for (int r = 0; r < 4; r++) {
                const int row = m0 + wm * 64 + mi * 16 + kg * 4 + r;
                if (row >= M) continue;
                if constexpr (MODE == 1) {
                    const float v = acc[mi][ni][r];
                    if (col < nsplit) {
                        Cf[(size_t)row * nsplit + col] = v + bv;
                    } else {
                        Chi[(size_t)row * (Nc - nsplit) + (col - nsplit)] = f2bf_rne(v);
                    }
                } else {
                    float g = 1.f;
                    if (gate) g = (gate[row] > 0) ? 1.f : 0.f;
                    float v = acc[mi][ni][r] + bv * g;
                    if (relu) v = fmaxf(v, 0.f);
                    const size_t o = (size_t)row * Nc + col;
                    if constexpr (MODE == 0) {
                        Cf[o] = v;
                    } else {
                        ushort h, l;
                        split2(v, h, l);
                        Chi[o] = h;
                        Clo[o] = l;
                    }
                }
            }
        }
    }
}

// ---------------- CSR mean aggregation ----------------
// ESPLIT=4 waves per node; each wave takes edges begin+sub, +4, ... ; LDS combine.
// S = mean_e relu(Ptop[n](f32) + Pbot[src_e](bf16)), written as hi/lo bf16.

template <int H>
__global__ __launch_bounds__(256) void agg_kernel(const float* __restrict__ Ptop,
                                                  const ushort* __restrict__ Pbot,
                                                  const int* __restrict__ row_ptr,
                                                  const int* __restrict__ csr,
                                                  ushort* __restrict__ Shi,
                                                  ushort* __restrict__ Slo, int N) {
    constexpr int VPL = H / 64;  // 4 or 2
    constexpr int ES = 4;
    __shared__ float red[ES - 1][64 * VPL];

    const int sub = threadIdx.x >> 6;
    const int lane = threadIdx.x & 63;
    const int n = blockIdx.x;

    const int begin = row_ptr[n];
    const int end = row_ptr[n + 1];

    float top[VPL], acc[VPL];
    if constexpr (VPL == 4) {
        float4 t = *(const float4*)(Ptop + (size_t)n * H + lane * 4);
        top[0] = t.x; top[1] = t.y; top[2] = t.z; top[3] = t.w;
    } else {
        float2 t = *(const float2*)(Ptop + (size_t)n * H + lane * 2);
        top[0] = t.x; top[1] = t.y;
    }
#pragma unroll
    for (int i = 0; i < VPL; i++) acc[i] = 0.f;

    int e = begin + sub;
    // 8 independent gathers in flight per wave
    while (e + 7 * ES < end) {
        int idx[8];
#pragma unroll
        for (int j = 0; j < 8; j++) idx[j] = csr[e + j * ES];
        if constexpr (VPL == 4) {
            ushort4 v[8];
#pragma unroll
            for (int j = 0; j < 8; j++)
                v[j] = *(const ushort4*)(Pbot + (size_t)idx[j] * H + lane * 4);
#pragma unroll
            for (int j = 0; j < 8; j++) {
                acc[0] += fmaxf(top[0] + bf2f(v[j].x), 0.f);
                acc[1] += fmaxf(top[1] + bf2f(v[j].y), 0.f);
                acc[2] += fmaxf(top[2] + bf2f(v[j].z), 0.f);
                acc[3] += fmaxf(top[3] + bf2f(v[j].w), 0.f);
            }
        } else {
            ushort2 v[8];
#pragma unroll
            for (int j = 0; j < 8; j++)
                v[j] = *(const ushort2*)(Pbot + (size_t)idx[j] * H + lane * 2);
#pragma unroll
            for (int j = 0; j < 8; j++) {
                acc[0] += fmaxf(top[0] + bf2f(v[j].x), 0.f);
                acc[1] += fmaxf(top[1] + bf2f(v[j].y), 0.f);
            }
        }
        e += 8 * ES;
    }
    for (; e < end; e += ES) {
        int s = csr[e];
        if constexpr (VPL == 4) {
            ushort4 v = *(const ushort4*)(Pbot + (size_t)s * H + lane * 4);
            acc[0] += fmaxf(top[0] + bf2f(v.x), 0.f);
            acc[1] += fmaxf(top[1] + bf2f(v.y), 0.f);
            acc[2] += fmaxf(top[2] + bf2f(v.z), 0.f);
            acc[3] += fmaxf(top[3] + bf2f(v.w), 0.f);
        } else {
            ushort2 v = *(const ushort2*)(Pbot + (size_t)s * H + lane * 2);
            acc[0] += fmaxf(top[0] + bf2f(v.x), 0.f);
            acc[1] += fmaxf(top[1] + bf2f(v.y), 0.f);
        }
    }

    if (sub != 0) {
#pragma unroll
        for (int i = 0; i < VPL; i++) red[sub - 1][lane * VPL + i] = acc[i];
    }
    __syncthreads();
    if (sub == 0) {
#pragma unroll
        for (int s = 0; s < ES - 1; s++)
#pragma unroll
            for (int i = 0; i < VPL; i++) acc[i] += red[s][lane * VPL + i];

        const float inv = (end > begin) ? 1.f / (float)(end - begin) : 0.f;
        if constexpr (VPL == 4) {
            ushort4 h, l;
            split2(acc[0] * inv, h.x, l.x);
            split2(acc[1] * inv, h.y, l.y);
            split2(acc[2] * inv, h.z, l.z);
            split2(acc[3] * inv, h.w, l.w);
            *(ushort4*)(Shi + (size_t)n * H + lane * 4) = h;
            *(ushort4*)(Slo + (size_t)n * H + lane * 4) = l;
        } else {
            ushort2 h, l;
            split2(acc[0] * inv, h.x, l.x);
            split2(acc[1] * inv, h.y, l.y);
            *(ushort2*)(Shi + (size_t)n * H + lane * 2) = h;
            *(ushort2*)(Slo + (size_t)n * H + lane * 2) = l;
        }
    }
}

// ---------------- launch ----------------

extern "C" void kernel_launch(void* const* d_in, const int* in_sizes, int n_in,
                              void* d_out, int out_size, void* d_ws, size_t ws_size,
                              hipStream_t stream) {
    const int N = in_sizes[0] / NODE_DIM;  // 20000
    const int E = in_sizes[1] / 2;         // 640000

    const float* x = (const float*)d_in[0];
    const int* ei = (const int*)d_in[1];
    const int* e_src = ei;
    const int* e_dst = ei + E;
    const float* W1a = (const float*)d_in[2];
    const float* b1a = (const float*)d_in[3];
    const float* W1b = (const float*)d_in[4];
    const float* b1b = (const float*)d_in[5];
    const float* W2a = (const float*)d_in[6];
    const float* b2a = (const float*)d_in[7];
    const float* W2b = (const float*)d_in[8];
    const float* b2b = (const float*)d_in[9];

    char* ws = (char*)d_ws;
    size_t off = 0;
    auto alloc = [&](size_t bytes) {
        size_t o = off;
        off += (bytes + 255) & ~(size_t)255;
        return o;
    };
    int* cnt = (int*)(ws + alloc((size_t)N * 4));
    int* row_ptr = (int*)(ws + alloc((size_t)(N + 1) * 4));
    int* cursor = (int*)(ws + alloc((size_t)N * 4));
    int* csr = (int*)(ws + alloc((size_t)E * 4));
    ushort* x_hi = (ushort*)(ws + alloc((size_t)N * NODE_DIM * 2));
    ushort* x_lo = (ushort*)(ws + alloc((size_t)N * NODE_DIM * 2));
    // merged transposed/split weights
    ushort* T1a_h = (ushort*)(ws + alloc((size_t)(2 * HID) * NODE_DIM * 2));  // [512][128]
    ushort* T1a_l = (ushort*)(ws + alloc((size_t)(2 * HID) * NODE_DIM * 2));
    ushort* T1b_h = (ushort*)(ws + alloc((size_t)HID * HID * 2));
    ushort* T1b_l = (ushort*)(ws + alloc((size_t)HID * HID * 2));
    ushort* T2a_h = (ushort*)(ws + alloc((size_t)(2 * OUTD) * HID * 2));  // [256][256]
    ushort* T2a_l = (ushort*)(ws + alloc((size_t)(2 * OUTD) * HID * 2));
    ushort* T2b_h = (ushort*)(ws + alloc((size_t)OUTD * OUTD * 2));
    ushort* T2b_l = (ushort*)(ws + alloc((size_t)OUTD * OUTD * 2));
    // activations
    float* P1t = (float*)(ws + alloc((size_t)N * HID * 4));
    ushort* P1b = (ushort*)(ws + alloc((size_t)N * HID * 2));
    ushort* S1h = (ushort*)(ws + alloc((size_t)N * HID * 2));
    ushort* S1l = (ushort*)(ws + alloc((size_t)N * HID * 2));
    ushort* h_hi = (ushort*)(ws + alloc((size_t)N * HID * 2));
    ushort* h_lo = (ushort*)(ws + alloc((size_t)N * HID * 2));
    float* P2t = P1t;
    ushort* P2b = P1b;
    ushort* S2h = S1h;
    ushort* S2l = S1l;

    // CSR build
    zero_int_kernel<<<(N + 255) / 256, 256, 0, stream>>>(cnt, N);
    hist_kernel<<<(E + 255) / 256, 256, 0, stream>>>(e_dst, cnt, E);
    scan_kernel<<<1, 1024, 0, stream>>>(cnt, row_ptr, cursor, N);
    scatter_kernel<<<(E + 255) / 256, 256, 0, stream>>>(e_src, e_dst, cursor, csr, E);

    // splits (merged weight buffers: rows [0,H) = top, [H,2H) = bottom)
    split_kernel<<<((N * NODE_DIM / 4) + 255) / 256, 256, 0, stream>>>(x, x_hi, x_lo, N * NODE_DIM / 4);
    tsplit_kernel<<<(HID * NODE_DIM + 255) / 256, 256, 0, stream>>>(W1a, 0, NODE_DIM, HID, HID, T1a_h, T1a_l);
    tsplit_kernel<<<(HID * NODE_DIM + 255) / 256, 256, 0, stream>>>(W1a, NODE_DIM, NODE_DIM, HID, HID,
                                                                    T1a_h + (size_t)HID * NODE_DIM,
                                                                    T1a_l + (size_t)HID * NODE_DIM);
    tsplit_kernel<<<(HID * HID + 255) / 256, 256, 0, stream>>>(W1b, 0, HID, HID, HID, T1b_h, T1b_l);
    tsplit_kernel<<<(OUTD * HID + 255) / 256, 256, 0, stream>>>(W2a, 0, HID, OUTD, OUTD, T2a_h, T2a_l);
    tsplit_kernel<<<(OUTD * HID + 255) / 256, 256, 0, stream>>>(W2a, HID, HID, OUTD, OUTD,
                                                                T2a_h + (size_t)OUTD * HID,
                                                                T2a_l + (size_t)OUTD * HID);
    tsplit_kernel<<<(OUTD * OUTD + 255) / 256, 256, 0, stream>>>(W2b, 0, OUTD, OUTD, OUTD, T2b_h, T2b_l);

    const int MT = (N + GBM - 1) / GBM;  // 157

    // Layer 1: merged projection (Nc=512: [P1t f32+b1a | P1b bf16])
    gemm_bf3<1><<<dim3(MT, (2 * HID) / GBN), 256, 0, stream>>>(
        x_hi, x_lo, N, NODE_DIM, T1a_h, T1a_l, b1a, nullptr, 0,
        P1t, P1b, nullptr, 2 * HID, HID);
    agg_kernel<HID><<<N, 256, 0, stream>>>(P1t, P1b, row_ptr, csr, S1h, S1l, N);
    gemm_bf3<2><<<dim3(MT, HID / GBN), 256, 0, stream>>>(
        S1h, S1l, N, HID, T1b_h, T1b_l, b1b, cnt, 1,
        nullptr, h_hi, h_lo, HID, 0);

    // Layer 2: merged projection (Nc=256: [P2t f32+b2a | P2b bf16])
    gemm_bf3<1><<<dim3(MT, (2 * OUTD) / GBN), 256, 0, stream>>>(
        h_hi, h_lo, N, HID, T2a_h, T2a_l, b2a, nullptr, 0,
        P2t, P2b, nullptr, 2 * OUTD, OUTD);
    agg_kernel<OUTD><<<N, 256, 0, stream>>>(P2t, P2b, row_ptr, csr, S2h, S2l, N);
    gemm_bf3<0><<<dim3(MT, OUTD / GBN), 256, 0, stream>>>(
        S2h, S2l, N, OUTD, T2b_h, T2b_l, b2b, cnt, 0,
        (float*)d_out, nullptr, nullptr, OUTD, 0);
}